// Round 8
// baseline (136.415 us; speedup 1.0000x reference)
//
#include <hip/hip_runtime.h>
#include <math.h>

// B=2, T=2048, D=768, H=12, HD=64
typedef __attribute__((ext_vector_type(8))) __bf16 bf16x8;
typedef __attribute__((ext_vector_type(4))) __bf16 bf16x4;
typedef __attribute__((ext_vector_type(4))) float f32x4;

#define GLOAD_LDS16(gsrc, ldst) \
  __builtin_amdgcn_global_load_lds((__attribute__((address_space(1))) const void*)(gsrc), \
                                   (__attribute__((address_space(3))) void*)(ldst), 16, 0, 0)

__device__ __forceinline__ float fexp2(float x) {
#if __has_builtin(__builtin_amdgcn_exp2f)
  return __builtin_amdgcn_exp2f(x);
#else
  return exp2f(x);
#endif
}

__global__ void cvt_bf16_kernel(const float* __restrict__ in, __bf16* __restrict__ out, int n4) {
  int i = blockIdx.x * 256 + threadIdx.x;
  if (i < n4) {
    float4 f = ((const float4*)in)[i];
    bf16x4 o;
    o[0] = (__bf16)f.x; o[1] = (__bf16)f.y; o[2] = (__bf16)f.z; o[3] = (__bf16)f.w;
    ((bf16x4*)out)[i] = o;
  }
}

// Tiled transpose-convert: out[C][R] = (bf16) in[R][C]. 32x32 tiles via LDS.
__global__ __launch_bounds__(256)
void cvtT_bf16_kernel(const float* __restrict__ in, __bf16* __restrict__ out, int R, int C) {
  __shared__ float t[32][33];
  int c0 = blockIdx.x * 32, r0 = blockIdx.y * 32;
  int tc = threadIdx.x & 31, tr = threadIdx.x >> 5;
#pragma unroll
  for (int i = 0; i < 4; ++i)
    t[tr + 8 * i][tc] = in[(size_t)(r0 + tr + 8 * i) * C + c0 + tc];
  __syncthreads();
#pragma unroll
  for (int i = 0; i < 4; ++i)
    out[(size_t)(c0 + tr + 8 * i) * R + r0 + tc] = (__bf16)t[tc][tr + 8 * i];
}

// TN GEMM: C[M][N] = A[M][K] * B[N][K]^T (+bias). BMxBN tile, BK=32, 4 waves
// (wave grid WGM x WGN). Small tiles -> many blocks -> 3-4.5 blocks/CU: TLP is
// what actually hides load latency. 3 LDS buffers, prefetch distance 2, raw
// s_barrier with COUNTED vmcnt (prefetch queue never drained mid-loop).
// Grid 1-D XCD-clustered: xcd = id&7 owns contiguous BM-row A-panels.
template<int EPI, int BM, int BN, int WGM, int WGN>
__global__ __launch_bounds__(256)
void gemm_tn_kernel(const __bf16* __restrict__ A, const __bf16* __restrict__ Bm,
                    const float* __restrict__ bias, float* __restrict__ outF,
                    __bf16* __restrict__ qo, __bf16* __restrict__ ko, __bf16* __restrict__ vo,
                    int M, int N, int K, int NBX) {
  constexpr int NSEGA = BM / 16, NSEGB = BN / 16;
  constexpr int NSEG = NSEGA + NSEGB;      // 16-row x 32-col segments per K-step
  constexpr int LPT  = NSEG / 4;           // global_load_lds per wave per stage
  constexpr int AM   = BM / 16 / WGM;      // m-frags per wave
  constexpr int BNF  = BN / 16 / WGN;      // n-frags per wave
  const int lane = threadIdx.x & 63;
  const int wave = threadIdx.x >> 6;
  const int r16 = lane & 15, g = lane >> 4;
  const int id = blockIdx.x;
  const int xcd = id & 7, slot = id >> 3;
  const int ppx = (int)(gridDim.x >> 3) / NBX;   // A-panels per XCD (grid%8==0)
  const int by = xcd * ppx + slot / NBX;
  const int bx = slot - (slot / NBX) * NBX;
  const int mBase = by * BM, nBase = bx * BN;
  __shared__ __align__(16) __bf16 lds[3][NSEG * 512];

  f32x4 acc[AM][BNF];
#pragma unroll
  for (int i = 0; i < AM; ++i)
#pragma unroll
    for (int j = 0; j < BNF; ++j) acc[i][j] = (f32x4){0.f, 0.f, 0.f, 0.f};

  const int mw = (wave / WGN) * AM;
  const int nw = (wave % WGN) * BNF;

  auto stage = [&](int ke, int b) {
#pragma unroll
    for (int i = 0; i < LPT; ++i) {
      int seg = wave * LPT + i;
      int isB = seg >= NSEGA;
      int t8 = isB ? seg - NSEGA : seg;
      int row = (isB ? nBase : mBase) + t8 * 16 + r16;
      const __bf16* src = (isB ? Bm : A) + (size_t)row * K + ke + g * 8;
      GLOAD_LDS16(src, &lds[b][seg * 512]);
    }
  };

  const int nt = K >> 5;
  stage(0, 0);
  stage(32, 1);
  int cur = 0;
  for (int t = 0; t < nt; ++t) {
    if (t + 1 < nt) asm volatile("s_waitcnt vmcnt(%0)" :: "i"(LPT) : "memory");
    else            asm volatile("s_waitcnt vmcnt(0)" ::: "memory");
    __builtin_amdgcn_sched_barrier(0);
    __builtin_amdgcn_s_barrier();
    __builtin_amdgcn_sched_barrier(0);
    int nxt = cur + 2; if (nxt >= 3) nxt -= 3;
    if (t + 2 < nt) stage((t + 2) << 5, nxt);
    const __bf16* L = lds[cur];
    bf16x8 af[AM], bfr[BNF];
#pragma unroll
    for (int i = 0; i < AM; ++i) af[i] = *(const bf16x8*)&L[((mw + i) * 64 + lane) * 8];
#pragma unroll
    for (int j = 0; j < BNF; ++j) bfr[j] = *(const bf16x8*)&L[((NSEGA + nw + j) * 64 + lane) * 8];
    __builtin_amdgcn_s_setprio(1);
#pragma unroll
    for (int i = 0; i < AM; ++i)
#pragma unroll
      for (int j = 0; j < BNF; ++j)
        acc[i][j] = __builtin_amdgcn_mfma_f32_16x16x32_bf16(af[i], bfr[j], acc[i][j], 0, 0, 0);
    __builtin_amdgcn_s_setprio(0);
    if (++cur == 3) cur = 0;
  }

#pragma unroll
  for (int i = 0; i < AM; ++i) {
#pragma unroll
    for (int j = 0; j < BNF; ++j) {
      int c = nBase + (nw + j) * 16 + r16;
      float bb = bias[c];
#pragma unroll
      for (int e = 0; e < 4; ++e) {
        int r = mBase + (mw + i) * 16 + g * 4 + e;
        float val = acc[i][j][e] + bb;
        if (EPI == 0) {
          int which = c / 768;             // 0:q 1:k 2:v
          int cc = c - which * 768;
          int hh = cc >> 6, dd = cc & 63;
          int bI = r >> 11, tt = r & 2047;
          if (which == 0) {
            // fold 1/sqrt(64) * log2(e) into q (softmax runs in exp2 space)
            qo[(((size_t)(bI * 12 + hh)) * 2048 + tt) * 64 + dd] = (__bf16)(val * 0.180336880f);
          } else if (which == 1) {
            ko[(((size_t)(bI * 12 + hh)) * 2048 + tt) * 64 + dd] = (__bf16)val;
          } else {
            vo[(((size_t)(bI * 12 + hh)) * 64 + dd) * 2048 + tt] = (__bf16)val;  // V^T [B,H,64,T]
          }
        } else {
          outF[(size_t)r * N + c] = val;
        }
      }
    }
  }
}

// Flash attention, causal, swapped-QK^T, O^T accumulation, causal-paired tiles.
// (unchanged from R6)
__global__ __launch_bounds__(128, 2)
void attn_kernel(const __bf16* __restrict__ qg, const __bf16* __restrict__ kg,
                 const __bf16* __restrict__ vtg, __bf16* __restrict__ yatt) {
  const int id = blockIdx.x;
  const int chunk = id & 7, within = id >> 3;   // XCD chunk = 3 heads (L2-resident K/V)
  const int bh = chunk * 3 + (within >> 5);
  const int a = within & 31, p = 63 - a;        // paired 32-row q-tiles
  const int Ka = (a >> 1) + 1, Kp = (p >> 1) + 1;
  const int lane = threadIdx.x & 63, wave = threadIdx.x >> 6;  // wave in {0,1}
  const int r16 = lane & 15, g = lane >> 4;
  const int bI = bh / 12, h = bh - bI * 12;
  const size_t headoff = (size_t)bh * 2048 * 64;
  const __bf16* Q = qg + headoff;
  const __bf16* Kh = kg + headoff;
  const __bf16* VT = vtg + headoff;             // [64][2048]

  __shared__ __align__(16) __bf16 Kbuf[2][4096];
  __shared__ __align__(16) __bf16 Vbuf[2][4096];
  __shared__ __align__(16) __bf16 Plds[2][16][72];

  const int rowA = a * 32 + wave * 16 + r16;
  const int rowP = p * 32 + wave * 16 + r16;
  bf16x8 qfa[2], qfp[2];
#pragma unroll
  for (int ks = 0; ks < 2; ++ks) {
    qfa[ks] = *(const bf16x8*)&Q[(size_t)rowA * 64 + ks * 32 + g * 8];
    qfp[ks] = *(const bf16x8*)&Q[(size_t)rowP * 64 + ks * 32 + g * 8];
  }

  int srow[4], scl[4];
#pragma unroll
  for (int i = 0; i < 4; ++i) {
    int c = (i * 2 + wave) * 64 + lane;
    srow[i] = c >> 3;
    scl[i] = (c & 7) ^ (srow[i] & 7);
  }
  auto stage = [&](int kt, int b) {
#pragma unroll
    for (int i = 0; i < 4; ++i) {
      GLOAD_LDS16(&Kh[(size_t)(kt * 64 + srow[i]) * 64 + scl[i] * 8], &Kbuf[b][(i * 2 + wave) * 512]);
      GLOAD_LDS16(&VT[(size_t)srow[i] * 2048 + kt * 64 + scl[i] * 8], &Vbuf[b][(i * 2 + wave) * 512]);
    }
  };

  f32x4 oa[4], op[4];
#pragma unroll
  for (int j = 0; j < 4; ++j) { oa[j] = (f32x4){0.f,0.f,0.f,0.f}; op[j] = (f32x4){0.f,0.f,0.f,0.f}; }
  float ma = -INFINITY, la = 0.f, mp = -INFINITY, lp = 0.f;

  auto process = [&](f32x4 (&st)[4], float& m, float& l, f32x4 (&o)[4],
                     bool domask, int rowq, int kt, const bf16x8 (&vf)[2][4]) {
    if (domask) {
#pragma unroll
      for (int j = 0; j < 4; ++j)
#pragma unroll
        for (int e = 0; e < 4; ++e)
          if (kt * 64 + j * 16 + 4 * g + e > rowq) st[j][e] = -INFINITY;
    }
    float mt = -INFINITY;
#pragma unroll
    for (int j = 0; j < 4; ++j)
#pragma unroll
      for (int e = 0; e < 4; ++e) mt = fmaxf(mt, st[j][e]);
    mt = fmaxf(mt, __shfl_xor(mt, 16, 64));
    mt = fmaxf(mt, __shfl_xor(mt, 32, 64));
    if (!__all(mt - m <= 8.f)) {
      float mn = fmaxf(m, mt);
      float alpha = fexp2(m - mn);
      m = mn;
      l *= alpha;
#pragma unroll
      for (int dj = 0; dj < 4; ++dj)
#pragma unroll
        for (int e = 0; e < 4; ++e) o[dj][e] *= alpha;
    }
    float ls = 0.f;
#pragma unroll
    for (int j = 0; j < 4; ++j)
#pragma unroll
      for (int e = 0; e < 4; ++e) {
        float pv = fexp2(st[j][e] - m);
        st[j][e] = pv;
        ls += pv;
      }
    ls += __shfl_xor(ls, 16, 64);
    ls += __shfl_xor(ls, 32, 64);
    l += ls;
#pragma unroll
    for (int j = 0; j < 4; ++j) {
      bf16x4 pk;
#pragma unroll
      for (int e = 0; e < 4; ++e) pk[e] = (__bf16)st[j][e];
      *(bf16x4*)&Plds[wave][r16][j * 16 + 4 * g] = pk;
    }
#pragma unroll
    for (int ks = 0; ks < 2; ++ks) {
      bf16x8 pf = *(const bf16x8*)&Plds[wave][r16][ks * 32 + g * 8];
#pragma unroll
      for (int dj = 0; dj < 4; ++dj)
        o[dj] = __builtin_amdgcn_mfma_f32_16x16x32_bf16(vf[ks][dj], pf, o[dj], 0, 0, 0);
    }
  };

  stage(0, 0);
  for (int kt = 0; kt < Kp; ++kt) {
    const int cur = kt & 1;
    __syncthreads();
    if (kt + 1 < Kp) stage(kt + 1, cur ^ 1);
    const bool dualA = (kt < Ka);
    f32x4 stp[4], sta[4];
#pragma unroll
    for (int j = 0; j < 4; ++j) { stp[j] = (f32x4){0.f,0.f,0.f,0.f}; sta[j] = (f32x4){0.f,0.f,0.f,0.f}; }
    __builtin_amdgcn_s_setprio(1);
#pragma unroll
    for (int ks = 0; ks < 2; ++ks)
#pragma unroll
      for (int j = 0; j < 4; ++j) {
        int row = j * 16 + r16;
        int cp = (ks * 4 + g) ^ (row & 7);
        bf16x8 kf = *(const bf16x8*)&Kbuf[cur][(row * 8 + cp) * 8];
        stp[j] = __builtin_amdgcn_mfma_f32_16x16x32_bf16(kf, qfp[ks], stp[j], 0, 0, 0);
        if (dualA) sta[j] = __builtin_amdgcn_mfma_f32_16x16x32_bf16(kf, qfa[ks], sta[j], 0, 0, 0);
      }
    __builtin_amdgcn_s_setprio(0);
    bf16x8 vf[2][4];
#pragma unroll
    for (int ks = 0; ks < 2; ++ks)
#pragma unroll
      for (int dj = 0; dj < 4; ++dj) {
        int row = dj * 16 + r16;
        int cp = (ks * 4 + g) ^ (row & 7);
        vf[ks][dj] = *(const bf16x8*)&Vbuf[cur][(row * 8 + cp) * 8];
      }
    process(stp, mp, lp, op, kt == Kp - 1, rowP, kt, vf);
    if (dualA) process(sta, ma, la, oa, kt == Ka - 1, rowA, kt, vf);
  }

  float invp = 1.0f / lp, inva = 1.0f / la;
#pragma unroll
  for (int dj = 0; dj < 4; ++dj) {
    bf16x4 ovp, ova;
#pragma unroll
    for (int e = 0; e < 4; ++e) { ovp[e] = (__bf16)(op[dj][e] * invp); ova[e] = (__bf16)(oa[dj][e] * inva); }
    *(bf16x4*)&yatt[((size_t)(bI * 2048 + rowP)) * 768 + h * 64 + dj * 16 + 4 * g] = ovp;
    *(bf16x4*)&yatt[((size_t)(bI * 2048 + rowA)) * 768 + h * 64 + dj * 16 + 4 * g] = ova;
  }
}

extern "C" void kernel_launch(void* const* d_in, const int* in_sizes, int n_in,
                              void* d_out, int out_size, void* d_ws, size_t ws_size,
                              hipStream_t stream) {
  (void)in_sizes; (void)n_in; (void)out_size; (void)ws_size;
  const float* x     = (const float*)d_in[0];
  const float* w_qkv = (const float*)d_in[1];
  const float* b_qkv = (const float*)d_in[2];
  const float* w_out = (const float*)d_in[3];
  const float* b_out = (const float*)d_in[4];
  float* out = (float*)d_out;

  char* ws = (char*)d_ws;
  __bf16* xb    = (__bf16*)(ws);              // [4096][768]
  __bf16* wqkvT = (__bf16*)(ws + 6291456);    // [2304][768]
  __bf16* woT   = (__bf16*)(ws + 9830400);    // [768][768]
  __bf16* qb    = (__bf16*)(ws + 11010048);   // [B,H,T,64]  (pre-scaled by 0.125*log2e)
  __bf16* kb    = (__bf16*)(ws + 17301504);   // [B,H,T,64]
  __bf16* vtb   = (__bf16*)(ws + 23592960);   // [B,H,64,T]  (V transposed)
  __bf16* yatt  = (__bf16*)(ws + 29884416);   // [4096][768]

  cvt_bf16_kernel<<<3072, 256, 0, stream>>>(x, xb, 786432);
  cvtT_bf16_kernel<<<dim3(72, 24), 256, 0, stream>>>(w_qkv, wqkvT, 768, 2304);
  cvtT_bf16_kernel<<<dim3(24, 24), 256, 0, stream>>>(w_out, woT, 768, 768);
  // QKV: 64x128 tiles -> (4096/64) x (2304/128) = 64 x 18 = 1152 blocks (4.5/CU)
  gemm_tn_kernel<0, 64, 128, 1, 4><<<1152, 256, 0, stream>>>(xb, wqkvT, b_qkv, nullptr,
                                                             qb, kb, vtb, 4096, 2304, 768, 18);
  attn_kernel<<<768, 128, 0, stream>>>(qb, kb, vtb, yatt);
  // out-proj: 64x64 tiles -> 64 x 12 = 768 blocks (3/CU)
  gemm_tn_kernel<1, 64, 64, 2, 2><<<768, 256, 0, stream>>>(yatt, woT, b_out, out,
                                                           nullptr, nullptr, nullptr, 4096, 768, 768, 12);
}

// Round 9
// 136.409 us; speedup vs baseline: 1.0000x; 1.0000x over previous
//
#include <hip/hip_runtime.h>
#include <math.h>

// B=2, T=2048, D=768, H=12, HD=64
typedef __attribute__((ext_vector_type(8))) __bf16 bf16x8;
typedef __attribute__((ext_vector_type(4))) __bf16 bf16x4;
typedef __attribute__((ext_vector_type(4))) float f32x4;

#define GLOAD_LDS16(gsrc, ldst) \
  __builtin_amdgcn_global_load_lds((__attribute__((address_space(1))) const void*)(gsrc), \
                                   (__attribute__((address_space(3))) void*)(ldst), 16, 0, 0)

__device__ __forceinline__ float fexp2(float x) {
#if __has_builtin(__builtin_amdgcn_exp2f)
  return __builtin_amdgcn_exp2f(x);
#else
  return exp2f(x);
#endif
}

__global__ void cvt_bf16_kernel(const float* __restrict__ in, __bf16* __restrict__ out, int n4) {
  int i = blockIdx.x * 256 + threadIdx.x;
  if (i < n4) {
    float4 f = ((const float4*)in)[i];
    bf16x4 o;
    o[0] = (__bf16)f.x; o[1] = (__bf16)f.y; o[2] = (__bf16)f.z; o[3] = (__bf16)f.w;
    ((bf16x4*)out)[i] = o;
  }
}

// Tiled transpose-convert: out[C][R] = (bf16) in[R][C]. 32x32 tiles via LDS.
__global__ __launch_bounds__(256)
void cvtT_bf16_kernel(const float* __restrict__ in, __bf16* __restrict__ out, int R, int C) {
  __shared__ float t[32][33];
  int c0 = blockIdx.x * 32, r0 = blockIdx.y * 32;
  int tc = threadIdx.x & 31, tr = threadIdx.x >> 5;
#pragma unroll
  for (int i = 0; i < 4; ++i)
    t[tr + 8 * i][tc] = in[(size_t)(r0 + tr + 8 * i) * C + c0 + tc];
  __syncthreads();
#pragma unroll
  for (int i = 0; i < 4; ++i)
    out[(size_t)(c0 + tr + 8 * i) * R + r0 + tc] = (__bf16)t[tc][tr + 8 * i];
}

// TN GEMM: C[M][N] = A[M][K] * B[N][K]^T (+bias). BMxBN tile, BK=64, 4 waves.
// m97-EXACT loop structure (the verified 874TF@4k structure, never tested here
// at BK=64 + single small buffer): per K-step {stage; barrier; compute; barrier}.
// Single buffer (16-24KB) -> 4-6 blocks/CU resident; the stage drain is covered
// by OTHER resident blocks (m114 wave-level overlap), not by in-block pipelining.
// 16-32 MFMA per barrier-period (BK=64) vs 8 at BK=32: density was the missing lever.
template<int EPI, int BM, int BN, int WGM, int WGN>
__global__ __launch_bounds__(256, 4)
void gemm_tn_kernel(const __bf16* __restrict__ A, const __bf16* __restrict__ Bm,
                    const float* __restrict__ bias, float* __restrict__ outF,
                    __bf16* __restrict__ qo, __bf16* __restrict__ ko, __bf16* __restrict__ vo,
                    int M, int N, int K, int NBX) {
  constexpr int NTA = BM / 16, NTB = BN / 16;   // 16-row tiles per side
  constexpr int NA = 2 * NTA;                   // A segments (2 k-halves)
  constexpr int NSEG = 2 * NTA + 2 * NTB;       // 1KB segments per K-step (BK=64)
  constexpr int LPT  = NSEG / 4;                // global_load_lds per thread per stage
  constexpr int AM   = NTA / WGM;               // m-frags per wave
  constexpr int BNF  = NTB / WGN;               // n-frags per wave
  const int lane = threadIdx.x & 63;
  const int wave = threadIdx.x >> 6;
  const int r16 = lane & 15, g = lane >> 4;
  const int id = blockIdx.x;
  const int xcd = id & 7, slot = id >> 3;
  const int ppx = (int)(gridDim.x >> 3) / NBX;   // A-panels per XCD (grid%8==0)
  const int by = xcd * ppx + slot / NBX;
  const int bx = slot - (slot / NBX) * NBX;
  const int mBase = by * BM, nBase = bx * BN;
  __shared__ __align__(16) __bf16 lds[NSEG * 512];   // single buffer

  f32x4 acc[AM][BNF];
#pragma unroll
  for (int i = 0; i < AM; ++i)
#pragma unroll
    for (int j = 0; j < BNF; ++j) acc[i][j] = (f32x4){0.f, 0.f, 0.f, 0.f};

  const int mw = (wave / WGN) * AM;
  const int nw = (wave % WGN) * BNF;

  // segment s<NA: A, ks=s/NTA, t8=s%NTA. s>=NA: B, sb=s-NA, ks=sb/NTB, t8=sb%NTB.
  auto stage = [&](int ke) {
#pragma unroll
    for (int i = 0; i < LPT; ++i) {
      int s = wave * LPT + i;
      int isB = (s >= NA);
      int sb = isB ? s - NA : s;
      int nt = isB ? NTB : NTA;
      int ks = sb / nt, t8 = sb - ks * nt;
      int row = (isB ? nBase : mBase) + t8 * 16 + r16;
      const __bf16* src = (isB ? Bm : A) + (size_t)row * K + ke + ks * 32 + g * 8;
      GLOAD_LDS16(src, &lds[s * 512]);
    }
  };

  const int ntk = K >> 6;
  for (int t = 0; t < ntk; ++t) {
    stage(t << 6);
    __syncthreads();                  // drains stage; all segs visible
#pragma unroll
    for (int ks = 0; ks < 2; ++ks) {
      bf16x8 af[AM], bfr[BNF];
#pragma unroll
      for (int i = 0; i < AM; ++i)
        af[i] = *(const bf16x8*)&lds[((ks * NTA + mw + i) * 64 + lane) * 8];
#pragma unroll
      for (int j = 0; j < BNF; ++j)
        bfr[j] = *(const bf16x8*)&lds[((NA + ks * NTB + nw + j) * 64 + lane) * 8];
      __builtin_amdgcn_s_setprio(1);
#pragma unroll
      for (int i = 0; i < AM; ++i)
#pragma unroll
        for (int j = 0; j < BNF; ++j)
          acc[i][j] = __builtin_amdgcn_mfma_f32_16x16x32_bf16(af[i], bfr[j], acc[i][j], 0, 0, 0);
      __builtin_amdgcn_s_setprio(0);
    }
    __syncthreads();                  // guards buffer reuse by next stage
  }

#pragma unroll
  for (int i = 0; i < AM; ++i) {
#pragma unroll
    for (int j = 0; j < BNF; ++j) {
      int c = nBase + (nw + j) * 16 + r16;
      float bb = bias[c];
#pragma unroll
      for (int e = 0; e < 4; ++e) {
        int r = mBase + (mw + i) * 16 + g * 4 + e;
        float val = acc[i][j][e] + bb;
        if (EPI == 0) {
          int which = c / 768;             // 0:q 1:k 2:v
          int cc = c - which * 768;
          int hh = cc >> 6, dd = cc & 63;
          int bI = r >> 11, tt = r & 2047;
          if (which == 0) {
            // fold 1/sqrt(64) * log2(e) into q (softmax runs in exp2 space)
            qo[(((size_t)(bI * 12 + hh)) * 2048 + tt) * 64 + dd] = (__bf16)(val * 0.180336880f);
          } else if (which == 1) {
            ko[(((size_t)(bI * 12 + hh)) * 2048 + tt) * 64 + dd] = (__bf16)val;
          } else {
            vo[(((size_t)(bI * 12 + hh)) * 64 + dd) * 2048 + tt] = (__bf16)val;  // V^T [B,H,64,T]
          }
        } else {
          outF[(size_t)r * N + c] = val;
        }
      }
    }
  }
}

// Flash attention, causal, swapped-QK^T, O^T accumulation, causal-paired tiles.
// (unchanged from R6 — isolated)
__global__ __launch_bounds__(128, 2)
void attn_kernel(const __bf16* __restrict__ qg, const __bf16* __restrict__ kg,
                 const __bf16* __restrict__ vtg, __bf16* __restrict__ yatt) {
  const int id = blockIdx.x;
  const int chunk = id & 7, within = id >> 3;   // XCD chunk = 3 heads (L2-resident K/V)
  const int bh = chunk * 3 + (within >> 5);
  const int a = within & 31, p = 63 - a;        // paired 32-row q-tiles
  const int Ka = (a >> 1) + 1, Kp = (p >> 1) + 1;
  const int lane = threadIdx.x & 63, wave = threadIdx.x >> 6;  // wave in {0,1}
  const int r16 = lane & 15, g = lane >> 4;
  const int bI = bh / 12, h = bh - bI * 12;
  const size_t headoff = (size_t)bh * 2048 * 64;
  const __bf16* Q = qg + headoff;
  const __bf16* Kh = kg + headoff;
  const __bf16* VT = vtg + headoff;             // [64][2048]

  __shared__ __align__(16) __bf16 Kbuf[2][4096];
  __shared__ __align__(16) __bf16 Vbuf[2][4096];
  __shared__ __align__(16) __bf16 Plds[2][16][72];

  const int rowA = a * 32 + wave * 16 + r16;
  const int rowP = p * 32 + wave * 16 + r16;
  bf16x8 qfa[2], qfp[2];
#pragma unroll
  for (int ks = 0; ks < 2; ++ks) {
    qfa[ks] = *(const bf16x8*)&Q[(size_t)rowA * 64 + ks * 32 + g * 8];
    qfp[ks] = *(const bf16x8*)&Q[(size_t)rowP * 64 + ks * 32 + g * 8];
  }

  int srow[4], scl[4];
#pragma unroll
  for (int i = 0; i < 4; ++i) {
    int c = (i * 2 + wave) * 64 + lane;
    srow[i] = c >> 3;
    scl[i] = (c & 7) ^ (srow[i] & 7);
  }
  auto stage = [&](int kt, int b) {
#pragma unroll
    for (int i = 0; i < 4; ++i) {
      GLOAD_LDS16(&Kh[(size_t)(kt * 64 + srow[i]) * 64 + scl[i] * 8], &Kbuf[b][(i * 2 + wave) * 512]);
      GLOAD_LDS16(&VT[(size_t)srow[i] * 2048 + kt * 64 + scl[i] * 8], &Vbuf[b][(i * 2 + wave) * 512]);
    }
  };

  f32x4 oa[4], op[4];
#pragma unroll
  for (int j = 0; j < 4; ++j) { oa[j] = (f32x4){0.f,0.f,0.f,0.f}; op[j] = (f32x4){0.f,0.f,0.f,0.f}; }
  float ma = -INFINITY, la = 0.f, mp = -INFINITY, lp = 0.f;

  auto process = [&](f32x4 (&st)[4], float& m, float& l, f32x4 (&o)[4],
                     bool domask, int rowq, int kt, const bf16x8 (&vf)[2][4]) {
    if (domask) {
#pragma unroll
      for (int j = 0; j < 4; ++j)
#pragma unroll
        for (int e = 0; e < 4; ++e)
          if (kt * 64 + j * 16 + 4 * g + e > rowq) st[j][e] = -INFINITY;
    }
    float mt = -INFINITY;
#pragma unroll
    for (int j = 0; j < 4; ++j)
#pragma unroll
      for (int e = 0; e < 4; ++e) mt = fmaxf(mt, st[j][e]);
    mt = fmaxf(mt, __shfl_xor(mt, 16, 64));
    mt = fmaxf(mt, __shfl_xor(mt, 32, 64));
    if (!__all(mt - m <= 8.f)) {
      float mn = fmaxf(m, mt);
      float alpha = fexp2(m - mn);
      m = mn;
      l *= alpha;
#pragma unroll
      for (int dj = 0; dj < 4; ++dj)
#pragma unroll
        for (int e = 0; e < 4; ++e) o[dj][e] *= alpha;
    }
    float ls = 0.f;
#pragma unroll
    for (int j = 0; j < 4; ++j)
#pragma unroll
      for (int e = 0; e < 4; ++e) {
        float pv = fexp2(st[j][e] - m);
        st[j][e] = pv;
        ls += pv;
      }
    ls += __shfl_xor(ls, 16, 64);
    ls += __shfl_xor(ls, 32, 64);
    l += ls;
#pragma unroll
    for (int j = 0; j < 4; ++j) {
      bf16x4 pk;
#pragma unroll
      for (int e = 0; e < 4; ++e) pk[e] = (__bf16)st[j][e];
      *(bf16x4*)&Plds[wave][r16][j * 16 + 4 * g] = pk;
    }
#pragma unroll
    for (int ks = 0; ks < 2; ++ks) {
      bf16x8 pf = *(const bf16x8*)&Plds[wave][r16][ks * 32 + g * 8];
#pragma unroll
      for (int dj = 0; dj < 4; ++dj)
        o[dj] = __builtin_amdgcn_mfma_f32_16x16x32_bf16(vf[ks][dj], pf, o[dj], 0, 0, 0);
    }
  };

  stage(0, 0);
  for (int kt = 0; kt < Kp; ++kt) {
    const int cur = kt & 1;
    __syncthreads();
    if (kt + 1 < Kp) stage(kt + 1, cur ^ 1);
    const bool dualA = (kt < Ka);
    f32x4 stp[4], sta[4];
#pragma unroll
    for (int j = 0; j < 4; ++j) { stp[j] = (f32x4){0.f,0.f,0.f,0.f}; sta[j] = (f32x4){0.f,0.f,0.f,0.f}; }
    __builtin_amdgcn_s_setprio(1);
#pragma unroll
    for (int ks = 0; ks < 2; ++ks)
#pragma unroll
      for (int j = 0; j < 4; ++j) {
        int row = j * 16 + r16;
        int cp = (ks * 4 + g) ^ (row & 7);
        bf16x8 kf = *(const bf16x8*)&Kbuf[cur][(row * 8 + cp) * 8];
        stp[j] = __builtin_amdgcn_mfma_f32_16x16x32_bf16(kf, qfp[ks], stp[j], 0, 0, 0);
        if (dualA) sta[j] = __builtin_amdgcn_mfma_f32_16x16x32_bf16(kf, qfa[ks], sta[j], 0, 0, 0);
      }
    __builtin_amdgcn_s_setprio(0);
    bf16x8 vf[2][4];
#pragma unroll
    for (int ks = 0; ks < 2; ++ks)
#pragma unroll
      for (int dj = 0; dj < 4; ++dj) {
        int row = dj * 16 + r16;
        int cp = (ks * 4 + g) ^ (row & 7);
        vf[ks][dj] = *(const bf16x8*)&Vbuf[cur][(row * 8 + cp) * 8];
      }
    process(stp, mp, lp, op, kt == Kp - 1, rowP, kt, vf);
    if (dualA) process(sta, ma, la, oa, kt == Ka - 1, rowA, kt, vf);
  }

  float invp = 1.0f / lp, inva = 1.0f / la;
#pragma unroll
  for (int dj = 0; dj < 4; ++dj) {
    bf16x4 ovp, ova;
#pragma unroll
    for (int e = 0; e < 4; ++e) { ovp[e] = (__bf16)(op[dj][e] * invp); ova[e] = (__bf16)(oa[dj][e] * inva); }
    *(bf16x4*)&yatt[((size_t)(bI * 2048 + rowP)) * 768 + h * 64 + dj * 16 + 4 * g] = ovp;
    *(bf16x4*)&yatt[((size_t)(bI * 2048 + rowA)) * 768 + h * 64 + dj * 16 + 4 * g] = ova;
  }
}

extern "C" void kernel_launch(void* const* d_in, const int* in_sizes, int n_in,
                              void* d_out, int out_size, void* d_ws, size_t ws_size,
                              hipStream_t stream) {
  (void)in_sizes; (void)n_in; (void)out_size; (void)ws_size;
  const float* x     = (const float*)d_in[0];
  const float* w_qkv = (const float*)d_in[1];
  const float* b_qkv = (const float*)d_in[2];
  const float* w_out = (const float*)d_in[3];
  const float* b_out = (const float*)d_in[4];
  float* out = (float*)d_out;

  char* ws = (char*)d_ws;
  __bf16* xb    = (__bf16*)(ws);              // [4096][768]
  __bf16* wqkvT = (__bf16*)(ws + 6291456);    // [2304][768]
  __bf16* woT   = (__bf16*)(ws + 9830400);    // [768][768]
  __bf16* qb    = (__bf16*)(ws + 11010048);   // [B,H,T,64]  (pre-scaled by 0.125*log2e)
  __bf16* kb    = (__bf16*)(ws + 17301504);   // [B,H,T,64]
  __bf16* vtb   = (__bf16*)(ws + 23592960);   // [B,H,64,T]  (V transposed)
  __bf16* yatt  = (__bf16*)(ws + 29884416);   // [4096][768]

  cvt_bf16_kernel<<<3072, 256, 0, stream>>>(x, xb, 786432);
  cvtT_bf16_kernel<<<dim3(72, 24), 256, 0, stream>>>(w_qkv, wqkvT, 768, 2304);
  cvtT_bf16_kernel<<<dim3(24, 24), 256, 0, stream>>>(w_out, woT, 768, 768);
  // QKV: 64x128 tiles, BK=64 -> 64 x 18 = 1152 blocks (4.5/CU), 24KB LDS
  gemm_tn_kernel<0, 64, 128, 1, 4><<<1152, 256, 0, stream>>>(xb, wqkvT, b_qkv, nullptr,
                                                             qb, kb, vtb, 4096, 2304, 768, 18);
  attn_kernel<<<768, 128, 0, stream>>>(qb, kb, vtb, yatt);
  // out-proj: 64x64 tiles, BK=64 -> 64 x 12 = 768 blocks (3/CU), 16KB LDS
  gemm_tn_kernel<1, 64, 64, 2, 2><<<768, 256, 0, stream>>>(yatt, woT, b_out, out,
                                                           nullptr, nullptr, nullptr, 4096, 768, 768, 12);
}

// Round 10
// 125.957 us; speedup vs baseline: 1.0830x; 1.0830x over previous
//
#include <hip/hip_runtime.h>
#include <math.h>

// B=2, T=2048, D=768, H=12, HD=64
typedef __attribute__((ext_vector_type(8))) __bf16 bf16x8;
typedef __attribute__((ext_vector_type(4))) __bf16 bf16x4;
typedef __attribute__((ext_vector_type(4))) float f32x4;

#define GLOAD_LDS16(gsrc, ldst) \
  __builtin_amdgcn_global_load_lds((__attribute__((address_space(1))) const void*)(gsrc), \
                                   (__attribute__((address_space(3))) void*)(ldst), 16, 0, 0)

__device__ __forceinline__ float fexp2(float x) {
#if __has_builtin(__builtin_amdgcn_exp2f)
  return __builtin_amdgcn_exp2f(x);
#else
  return exp2f(x);
#endif
}

__global__ void cvt_bf16_kernel(const float* __restrict__ in, __bf16* __restrict__ out, int n4) {
  int i = blockIdx.x * 256 + threadIdx.x;
  if (i < n4) {
    float4 f = ((const float4*)in)[i];
    bf16x4 o;
    o[0] = (__bf16)f.x; o[1] = (__bf16)f.y; o[2] = (__bf16)f.z; o[3] = (__bf16)f.w;
    ((bf16x4*)out)[i] = o;
  }
}

// Tiled transpose-convert: out[C][R] = (bf16) in[R][C]. 32x32 tiles via LDS.
__global__ __launch_bounds__(256)
void cvtT_bf16_kernel(const float* __restrict__ in, __bf16* __restrict__ out, int R, int C) {
  __shared__ float t[32][33];
  int c0 = blockIdx.x * 32, r0 = blockIdx.y * 32;
  int tc = threadIdx.x & 31, tr = threadIdx.x >> 5;
#pragma unroll
  for (int i = 0; i < 4; ++i)
    t[tr + 8 * i][tc] = in[(size_t)(r0 + tr + 8 * i) * C + c0 + tc];
  __syncthreads();
#pragma unroll
  for (int i = 0; i < 4; ++i)
    out[(size_t)(c0 + tr + 8 * i) * R + r0 + tc] = (__bf16)t[tc][tr + 8 * i];
}

// TN GEMM: C[M][N] = A[M][K] * B[N][K]^T (+bias). 128x192 tile, BK=64, 8 waves
// (2x4 wave grid; 4 m-frags x 3 n-frags = 24 MFMA per phase per wave).
// FAT-TILE rationale (R9 post-mortem): global->LDS staging throughput (~22B/cy/CU)
// was the invariant limiter across R6-R9; staged-bytes per FLOP is the lever.
// 128x192 = 12.7 B/KFLOP vs 23.4 at 64x128.  3 LDS buffers (40KB each = 120KB),
// prefetch distance 2, raw s_barrier + COUNTED vmcnt (R7's validated pipeline).
template<int EPI>
__global__ __launch_bounds__(512, 2)
void gemm_tn_kernel(const __bf16* __restrict__ A, const __bf16* __restrict__ Bm,
                    const float* __restrict__ bias, float* __restrict__ outF,
                    __bf16* __restrict__ qo, __bf16* __restrict__ ko, __bf16* __restrict__ vo,
                    int M, int N, int K, int NBX) {
  constexpr int NTA = 8, NTB = 12;          // 16-row tiles: BM=128, BN=192
  constexpr int NA = 2 * NTA;               // A segments (2 k-halves)
  constexpr int NSEG = 2 * NTA + 2 * NTB;   // 40 x 1KB segments per K-step
  constexpr int LPT = NSEG / 8;             // 5 global_load_lds per thread per stage
  const int lane = threadIdx.x & 63;
  const int wave = threadIdx.x >> 6;        // 0..7
  const int r16 = lane & 15, g = lane >> 4;
  const int id = blockIdx.x;
  const int xcd = id & 7, slot = id >> 3;
  const int ppx = (int)(gridDim.x >> 3) / NBX;   // A-panels per XCD (grid%8==0)
  const int by = xcd * ppx + slot / NBX;
  const int bx = slot - (slot / NBX) * NBX;
  const int mBase = by * 128, nBase = bx * 192;
  __shared__ __align__(16) __bf16 lds[3][NSEG * 512];   // 120 KB

  f32x4 acc[4][3];
#pragma unroll
  for (int i = 0; i < 4; ++i)
#pragma unroll
    for (int j = 0; j < 3; ++j) acc[i][j] = (f32x4){0.f, 0.f, 0.f, 0.f};

  const int mw = (wave >> 2) * 4;   // m-frag base (0 or 4)
  const int nw = (wave & 3) * 3;    // n-frag base (0,3,6,9)

  auto stage = [&](int ke, int b) {
#pragma unroll
    for (int i = 0; i < LPT; ++i) {
      int s = wave * LPT + i;
      int isB = (s >= NA);
      int sb = isB ? s - NA : s;
      int nt = isB ? NTB : NTA;
      int ks = sb / nt, t8 = sb - ks * nt;
      int row = (isB ? nBase : mBase) + t8 * 16 + r16;
      const __bf16* src = (isB ? Bm : A) + (size_t)row * K + ke + ks * 32 + g * 8;
      GLOAD_LDS16(src, &lds[b][s * 512]);
    }
  };

  const int nt = K >> 6;
  stage(0, 0);
  stage(64, 1);
  int cur = 0;
  for (int t = 0; t < nt; ++t) {
    if (t + 1 < nt) asm volatile("s_waitcnt vmcnt(%0)" :: "i"(LPT) : "memory");
    else            asm volatile("s_waitcnt vmcnt(0)" ::: "memory");
    __builtin_amdgcn_sched_barrier(0);
    __builtin_amdgcn_s_barrier();
    __builtin_amdgcn_sched_barrier(0);
    int nxt = cur + 2; if (nxt >= 3) nxt -= 3;
    if (t + 2 < nt) stage((t + 2) << 6, nxt);
    const __bf16* L = lds[cur];
#pragma unroll
    for (int ks = 0; ks < 2; ++ks) {
      bf16x8 af[4], bfr[3];
#pragma unroll
      for (int i = 0; i < 4; ++i)
        af[i] = *(const bf16x8*)&L[((ks * NTA + mw + i) * 64 + lane) * 8];
#pragma unroll
      for (int j = 0; j < 3; ++j)
        bfr[j] = *(const bf16x8*)&L[((NA + ks * NTB + nw + j) * 64 + lane) * 8];
      __builtin_amdgcn_s_setprio(1);
#pragma unroll
      for (int i = 0; i < 4; ++i)
#pragma unroll
        for (int j = 0; j < 3; ++j)
          acc[i][j] = __builtin_amdgcn_mfma_f32_16x16x32_bf16(af[i], bfr[j], acc[i][j], 0, 0, 0);
      __builtin_amdgcn_s_setprio(0);
    }
    if (++cur == 3) cur = 0;
  }

#pragma unroll
  for (int i = 0; i < 4; ++i) {
#pragma unroll
    for (int j = 0; j < 3; ++j) {
      int c = nBase + (nw + j) * 16 + r16;
      float bb = bias[c];
#pragma unroll
      for (int e = 0; e < 4; ++e) {
        int r = mBase + (mw + i) * 16 + g * 4 + e;
        float val = acc[i][j][e] + bb;
        if (EPI == 0) {
          int which = c / 768;             // 0:q 1:k 2:v  (BN=192 divides 768)
          int cc = c - which * 768;
          int hh = cc >> 6, dd = cc & 63;
          int bI = r >> 11, tt = r & 2047;
          if (which == 0) {
            // fold 1/sqrt(64) * log2(e) into q (softmax runs in exp2 space)
            qo[(((size_t)(bI * 12 + hh)) * 2048 + tt) * 64 + dd] = (__bf16)(val * 0.180336880f);
          } else if (which == 1) {
            ko[(((size_t)(bI * 12 + hh)) * 2048 + tt) * 64 + dd] = (__bf16)val;
          } else {
            vo[(((size_t)(bI * 12 + hh)) * 64 + dd) * 2048 + tt] = (__bf16)val;  // V^T [B,H,64,T]
          }
        } else {
          outF[(size_t)r * N + c] = val;
        }
      }
    }
  }
}

// Flash attention, causal, swapped-QK^T, O^T accumulation, causal-paired tiles.
// (unchanged from R6 — isolated)
__global__ __launch_bounds__(128, 2)
void attn_kernel(const __bf16* __restrict__ qg, const __bf16* __restrict__ kg,
                 const __bf16* __restrict__ vtg, __bf16* __restrict__ yatt) {
  const int id = blockIdx.x;
  const int chunk = id & 7, within = id >> 3;   // XCD chunk = 3 heads (L2-resident K/V)
  const int bh = chunk * 3 + (within >> 5);
  const int a = within & 31, p = 63 - a;        // paired 32-row q-tiles
  const int Ka = (a >> 1) + 1, Kp = (p >> 1) + 1;
  const int lane = threadIdx.x & 63, wave = threadIdx.x >> 6;  // wave in {0,1}
  const int r16 = lane & 15, g = lane >> 4;
  const int bI = bh / 12, h = bh - bI * 12;
  const size_t headoff = (size_t)bh * 2048 * 64;
  const __bf16* Q = qg + headoff;
  const __bf16* Kh = kg + headoff;
  const __bf16* VT = vtg + headoff;             // [64][2048]

  __shared__ __align__(16) __bf16 Kbuf[2][4096];
  __shared__ __align__(16) __bf16 Vbuf[2][4096];
  __shared__ __align__(16) __bf16 Plds[2][16][72];

  const int rowA = a * 32 + wave * 16 + r16;
  const int rowP = p * 32 + wave * 16 + r16;
  bf16x8 qfa[2], qfp[2];
#pragma unroll
  for (int ks = 0; ks < 2; ++ks) {
    qfa[ks] = *(const bf16x8*)&Q[(size_t)rowA * 64 + ks * 32 + g * 8];
    qfp[ks] = *(const bf16x8*)&Q[(size_t)rowP * 64 + ks * 32 + g * 8];
  }

  int srow[4], scl[4];
#pragma unroll
  for (int i = 0; i < 4; ++i) {
    int c = (i * 2 + wave) * 64 + lane;
    srow[i] = c >> 3;
    scl[i] = (c & 7) ^ (srow[i] & 7);
  }
  auto stage = [&](int kt, int b) {
#pragma unroll
    for (int i = 0; i < 4; ++i) {
      GLOAD_LDS16(&Kh[(size_t)(kt * 64 + srow[i]) * 64 + scl[i] * 8], &Kbuf[b][(i * 2 + wave) * 512]);
      GLOAD_LDS16(&VT[(size_t)srow[i] * 2048 + kt * 64 + scl[i] * 8], &Vbuf[b][(i * 2 + wave) * 512]);
    }
  };

  f32x4 oa[4], op[4];
#pragma unroll
  for (int j = 0; j < 4; ++j) { oa[j] = (f32x4){0.f,0.f,0.f,0.f}; op[j] = (f32x4){0.f,0.f,0.f,0.f}; }
  float ma = -INFINITY, la = 0.f, mp = -INFINITY, lp = 0.f;

  auto process = [&](f32x4 (&st)[4], float& m, float& l, f32x4 (&o)[4],
                     bool domask, int rowq, int kt, const bf16x8 (&vf)[2][4]) {
    if (domask) {
#pragma unroll
      for (int j = 0; j < 4; ++j)
#pragma unroll
        for (int e = 0; e < 4; ++e)
          if (kt * 64 + j * 16 + 4 * g + e > rowq) st[j][e] = -INFINITY;
    }
    float mt = -INFINITY;
#pragma unroll
    for (int j = 0; j < 4; ++j)
#pragma unroll
      for (int e = 0; e < 4; ++e) mt = fmaxf(mt, st[j][e]);
    mt = fmaxf(mt, __shfl_xor(mt, 16, 64));
    mt = fmaxf(mt, __shfl_xor(mt, 32, 64));
    if (!__all(mt - m <= 8.f)) {
      float mn = fmaxf(m, mt);
      float alpha = fexp2(m - mn);
      m = mn;
      l *= alpha;
#pragma unroll
      for (int dj = 0; dj < 4; ++dj)
#pragma unroll
        for (int e = 0; e < 4; ++e) o[dj][e] *= alpha;
    }
    float ls = 0.f;
#pragma unroll
    for (int j = 0; j < 4; ++j)
#pragma unroll
      for (int e = 0; e < 4; ++e) {
        float pv = fexp2(st[j][e] - m);
        st[j][e] = pv;
        ls += pv;
      }
    ls += __shfl_xor(ls, 16, 64);
    ls += __shfl_xor(ls, 32, 64);
    l += ls;
#pragma unroll
    for (int j = 0; j < 4; ++j) {
      bf16x4 pk;
#pragma unroll
      for (int e = 0; e < 4; ++e) pk[e] = (__bf16)st[j][e];
      *(bf16x4*)&Plds[wave][r16][j * 16 + 4 * g] = pk;
    }
#pragma unroll
    for (int ks = 0; ks < 2; ++ks) {
      bf16x8 pf = *(const bf16x8*)&Plds[wave][r16][ks * 32 + g * 8];
#pragma unroll
      for (int dj = 0; dj < 4; ++dj)
        o[dj] = __builtin_amdgcn_mfma_f32_16x16x32_bf16(vf[ks][dj], pf, o[dj], 0, 0, 0);
    }
  };

  stage(0, 0);
  for (int kt = 0; kt < Kp; ++kt) {
    const int cur = kt & 1;
    __syncthreads();
    if (kt + 1 < Kp) stage(kt + 1, cur ^ 1);
    const bool dualA = (kt < Ka);
    f32x4 stp[4], sta[4];
#pragma unroll
    for (int j = 0; j < 4; ++j) { stp[j] = (f32x4){0.f,0.f,0.f,0.f}; sta[j] = (f32x4){0.f,0.f,0.f,0.f}; }
    __builtin_amdgcn_s_setprio(1);
#pragma unroll
    for (int ks = 0; ks < 2; ++ks)
#pragma unroll
      for (int j = 0; j < 4; ++j) {
        int row = j * 16 + r16;
        int cp = (ks * 4 + g) ^ (row & 7);
        bf16x8 kf = *(const bf16x8*)&Kbuf[cur][(row * 8 + cp) * 8];
        stp[j] = __builtin_amdgcn_mfma_f32_16x16x32_bf16(kf, qfp[ks], stp[j], 0, 0, 0);
        if (dualA) sta[j] = __builtin_amdgcn_mfma_f32_16x16x32_bf16(kf, qfa[ks], sta[j], 0, 0, 0);
      }
    __builtin_amdgcn_s_setprio(0);
    bf16x8 vf[2][4];
#pragma unroll
    for (int ks = 0; ks < 2; ++ks)
#pragma unroll
      for (int dj = 0; dj < 4; ++dj) {
        int row = dj * 16 + r16;
        int cp = (ks * 4 + g) ^ (row & 7);
        vf[ks][dj] = *(const bf16x8*)&Vbuf[cur][(row * 8 + cp) * 8];
      }
    process(stp, mp, lp, op, kt == Kp - 1, rowP, kt, vf);
    if (dualA) process(sta, ma, la, oa, kt == Ka - 1, rowA, kt, vf);
  }

  float invp = 1.0f / lp, inva = 1.0f / la;
#pragma unroll
  for (int dj = 0; dj < 4; ++dj) {
    bf16x4 ovp, ova;
#pragma unroll
    for (int e = 0; e < 4; ++e) { ovp[e] = (__bf16)(op[dj][e] * invp); ova[e] = (__bf16)(oa[dj][e] * inva); }
    *(bf16x4*)&yatt[((size_t)(bI * 2048 + rowP)) * 768 + h * 64 + dj * 16 + 4 * g] = ovp;
    *(bf16x4*)&yatt[((size_t)(bI * 2048 + rowA)) * 768 + h * 64 + dj * 16 + 4 * g] = ova;
  }
}

extern "C" void kernel_launch(void* const* d_in, const int* in_sizes, int n_in,
                              void* d_out, int out_size, void* d_ws, size_t ws_size,
                              hipStream_t stream) {
  (void)in_sizes; (void)n_in; (void)out_size; (void)ws_size;
  const float* x     = (const float*)d_in[0];
  const float* w_qkv = (const float*)d_in[1];
  const float* b_qkv = (const float*)d_in[2];
  const float* w_out = (const float*)d_in[3];
  const float* b_out = (const float*)d_in[4];
  float* out = (float*)d_out;

  char* ws = (char*)d_ws;
  __bf16* xb    = (__bf16*)(ws);              // [4096][768]
  __bf16* wqkvT = (__bf16*)(ws + 6291456);    // [2304][768]
  __bf16* woT   = (__bf16*)(ws + 9830400);    // [768][768]
  __bf16* qb    = (__bf16*)(ws + 11010048);   // [B,H,T,64]  (pre-scaled by 0.125*log2e)
  __bf16* kb    = (__bf16*)(ws + 17301504);   // [B,H,T,64]
  __bf16* vtb   = (__bf16*)(ws + 23592960);   // [B,H,64,T]  (V transposed)
  __bf16* yatt  = (__bf16*)(ws + 29884416);   // [4096][768]

  cvt_bf16_kernel<<<3072, 256, 0, stream>>>(x, xb, 786432);
  cvtT_bf16_kernel<<<dim3(72, 24), 256, 0, stream>>>(w_qkv, wqkvT, 768, 2304);
  cvtT_bf16_kernel<<<dim3(24, 24), 256, 0, stream>>>(w_out, woT, 768, 768);
  // QKV: 128x192 tiles -> 32 x 12 = 384 blocks = 8 XCD x 48
  gemm_tn_kernel<0><<<384, 512, 0, stream>>>(xb, wqkvT, b_qkv, nullptr,
                                             qb, kb, vtb, 4096, 2304, 768, 12);
  attn_kernel<<<768, 128, 0, stream>>>(qb, kb, vtb, yatt);
  // out-proj: 128x192 tiles -> 32 x 4 = 128 blocks = 8 XCD x 16
  gemm_tn_kernel<1><<<128, 512, 0, stream>>>(yatt, woT, b_out, out,
                                             nullptr, nullptr, nullptr, 4096, 768, 768, 4);
}